// Round 10
// baseline (622.411 us; speedup 1.0000x reference)
//
#include <hip/hip_runtime.h>
#include <hip/hip_bf16.h>

#define NN 50000
#define EE 1600000
#define DD 512
#define HH 256
#define GG 16
#define BK 96     // bucket capacity (deg ~ Poisson(32), P(>=96) ~ 1e-18)
#define NCH 256   // edge chunks
#define CHSZ 6250 // EE / NCH

typedef __attribute__((ext_vector_type(8))) short bf16x8;
typedef __attribute__((ext_vector_type(4))) float f32x4;
typedef __attribute__((ext_vector_type(2))) float f32x2;

__device__ __forceinline__ unsigned short f2b(float f) {
    union { float f; unsigned int u; } v; v.f = f;
    unsigned int r = v.u + 0x7fffu + ((v.u >> 16) & 1u);
    return (unsigned short)(r >> 16);
}
__device__ __forceinline__ float b2f(unsigned short s) {
    union { unsigned int i; float f; } v; v.i = ((unsigned int)s) << 16; return v.f;
}
__device__ __forceinline__ unsigned char f2fp8(float f) {
    return (unsigned char)(__builtin_amdgcn_cvt_pk_fp8_f32(f, f, 0, false) & 0xff);
}

// ---------------- pass 1: per-chunk dst histograms (LDS atomics only) ----------------
// block b: chunk j=b>>1, dst-half h=b&1. hist[j][d] as packed u16 pairs (dword index j*25000 + d/2)
__global__ __launch_bounds__(256) void k_hist(const int* __restrict__ ei, unsigned int* __restrict__ histg) {
    __shared__ unsigned int hp[12500];
    int b = blockIdx.x, t = threadIdx.x;
    int j = b >> 1, half = b & 1;
    int dlo = half * 25000;
    for (int i = t; i < 12500; i += 256) hp[i] = 0;
    __syncthreads();
    int base = j * CHSZ;
    for (int k = 0; k < 25; ++k) {
        int o = k * 256 + t;
        if (o < CHSZ) {
            int d = ei[EE + base + o];
            unsigned int ld = (unsigned)(d - dlo);
            if (ld < 25000u) atomicAdd(&hp[ld >> 1], (ld & 1) ? 65536u : 1u);
        }
    }
    __syncthreads();
    unsigned int* dst = histg + j * 25000 + half * 12500;
    for (int i = t; i < 12500; i += 256) dst[i] = hp[i];
}

// ---------------- pass 2: per-chunk exclusive offsets + cnt/dinv | x->bf16 | W->bf16^T ----------------
// blocks [0,98): offsets. [98,6348): x convert. [6348,7372): weight transpose-convert.
__global__ __launch_bounds__(256) void k_off_cvt(const unsigned int* __restrict__ histg,
                                                 unsigned int* __restrict__ offg,
                                                 int* __restrict__ cnt, float* __restrict__ dinv,
                                                 const float* __restrict__ x, unsigned short* __restrict__ xb,
                                                 const float* __restrict__ W1, const float* __restrict__ W2,
                                                 const float* __restrict__ W3, unsigned short* __restrict__ W1t,
                                                 unsigned short* __restrict__ W2t, unsigned short* __restrict__ W3t) {
    int b = blockIdx.x, t = threadIdx.x;
    if (b < 98) {
        int i = b * 256 + t;
        if (i < 25000) {
            unsigned run0 = 0, run1 = 0;
            #pragma unroll 8
            for (int j = 0; j < NCH; ++j) {
                unsigned h = histg[j * 25000 + i];
                offg[j * 25000 + i] = run0 | (run1 << 16);   // exclusive prefix (fits u16: deg<=~70)
                run0 += h & 0xffffu; run1 += h >> 16;
            }
            int d0 = 2 * i, d1 = 2 * i + 1;
            cnt[d0] = (int)run0; cnt[d1] = (int)run1;
            dinv[d0] = rsqrtf((float)run0 + 1.0f);
            dinv[d1] = rsqrtf((float)run1 + 1.0f);
        }
    } else if (b < 6348) {
        size_t i0 = (size_t)(b - 98) * 1024 + t;
        #pragma unroll
        for (int k = 0; k < 4; ++k) {
            size_t i = i0 + (size_t)k * 256;
            float4 v = *(const float4*)(x + i * 4);
            ushort4 o;
            o.x = f2b(v.x); o.y = f2b(v.y); o.z = f2b(v.z); o.w = f2b(v.w);
            *(ushort4*)(xb + i * 4) = o;
        }
    } else {
        int u = (b - 6348) * 256 + t;
        if (u < 131072) {
            int k = u >> 8, n = u & 255;
            W1t[(size_t)n * 512 + k] = f2b(W1[u]);
        } else if (u < 196608) {
            int q = u - 131072; int k = q >> 8, n = q & 255;
            W2t[(size_t)n * 256 + k] = f2b(W2[q]);
        } else {
            int q = u - 196608; int k = q >> 8, n = q & 255;
            W3t[(size_t)n * 256 + k] = f2b(W3[q]);
        }
    }
}

// ---------------- pass 3: atomic-free placement (XCD-partitioned) | fused GEMM layer 1 ----------------
// blocks [0,2048): place. block b: chunk j=b>>3, dst-range x8=b&7 (%8 XCD heuristic; correct
//   under any mapping). rank via LDS cursor; pos = off[j][d] + rank; plain u16 store.
// blocks [2048,2830): bf16 MFMA GEMM layer 1 (xb @ W1t^T -> fp8 mb), flattened 391x2.
__global__ __launch_bounds__(256) void k_place_gemm1(const int* __restrict__ ei,
                                                     const unsigned int* __restrict__ offg,
                                                     unsigned short* __restrict__ bucket,
                                                     const unsigned short* __restrict__ A,
                                                     const unsigned short* __restrict__ Bt,
                                                     const float* __restrict__ dinv,
                                                     unsigned char* __restrict__ C) {
    __shared__ unsigned int cur[3125];
    __shared__ unsigned short As[128 * 32];
    __shared__ unsigned short Bs[128 * 32];
    int b = blockIdx.x, t = threadIdx.x;
    if (b < 2048) {
        int x8 = b & 7, j = b >> 3;
        int lo = x8 * CHSZ;                 // 6250-node range; lo even so parity(ld)==parity(d)
        for (int i = t; i < 3125; i += 256) cur[i] = 0;
        __syncthreads();
        int base = j * CHSZ;
        for (int k = 0; k < 25; ++k) {
            int o = k * 256 + t;
            if (o < CHSZ) {
                int d = ei[EE + base + o];
                unsigned ld = (unsigned)(d - lo);
                if (ld < 6250u) {
                    int s = ei[base + o];
                    unsigned old = atomicAdd(&cur[ld >> 1], (ld & 1) ? 65536u : 1u);
                    unsigned rank = (ld & 1) ? (old >> 16) : (old & 0xffffu);
                    unsigned ov = offg[j * 25000 + (d >> 1)];
                    unsigned pos = ((d & 1) ? (ov >> 16) : (ov & 0xffffu)) + rank;
                    if (pos < BK) bucket[(size_t)d * BK + pos] = (unsigned short)s;
                }
            }
        }
        return;
    }
    // ---- GEMM layer 1 ----
    int gb = b - 2048;
    const int M = NN, K = DD;
    const int wave = t >> 6;
    const int lane = t & 63;
    const int row0 = (gb >> 1) * 128;
    const int col0 = (gb & 1) * 128;
    const int wr = wave & 1;
    const int wc = wave >> 1;
    const int l15 = lane & 15;
    const int quad = lane >> 4;
    const int sr = t >> 2;
    const int sk = (t & 3) * 8;

    int ar0 = row0 + sr;        if (ar0 >= M) ar0 = M - 1;
    int ar1 = row0 + 64 + sr;   if (ar1 >= M) ar1 = M - 1;
    const int bc0 = col0 + sr;
    const int bc1 = col0 + 64 + sr;

    f32x4 acc[4][4];
    #pragma unroll
    for (int i = 0; i < 4; ++i)
        #pragma unroll
        for (int jj = 0; jj < 4; ++jj)
            acc[i][jj] = (f32x4){0.f, 0.f, 0.f, 0.f};

    for (int kb = 0; kb < K; kb += 32) {
        const unsigned short* ga0 = A + (size_t)ar0 * K + kb + sk;
        const unsigned short* ga1 = A + (size_t)ar1 * K + kb + sk;
        const unsigned short* gb0 = Bt + (size_t)bc0 * K + kb + sk;
        const unsigned short* gb1 = Bt + (size_t)bc1 * K + kb + sk;
        __builtin_amdgcn_global_load_lds((const __attribute__((address_space(1))) void*)ga0,
            (__attribute__((address_space(3))) void*)&As[wave * 512], 16, 0, 0);
        __builtin_amdgcn_global_load_lds((const __attribute__((address_space(1))) void*)ga1,
            (__attribute__((address_space(3))) void*)&As[2048 + wave * 512], 16, 0, 0);
        __builtin_amdgcn_global_load_lds((const __attribute__((address_space(1))) void*)gb0,
            (__attribute__((address_space(3))) void*)&Bs[wave * 512], 16, 0, 0);
        __builtin_amdgcn_global_load_lds((const __attribute__((address_space(1))) void*)gb1,
            (__attribute__((address_space(3))) void*)&Bs[2048 + wave * 512], 16, 0, 0);
        __syncthreads();

        bf16x8 af[4], bfr[4];
        #pragma unroll
        for (int mi = 0; mi < 4; ++mi)
            af[mi] = *(const bf16x8*)&As[(wr * 64 + mi * 16 + l15) * 32 + quad * 8];
        #pragma unroll
        for (int ni = 0; ni < 4; ++ni)
            bfr[ni] = *(const bf16x8*)&Bs[(wc * 64 + ni * 16 + l15) * 32 + quad * 8];
        #pragma unroll
        for (int mi = 0; mi < 4; ++mi)
            #pragma unroll
            for (int ni = 0; ni < 4; ++ni)
                acc[mi][ni] = __builtin_amdgcn_mfma_f32_16x16x32_bf16(af[mi], bfr[ni], acc[mi][ni], 0, 0, 0);
        __syncthreads();
    }

    #pragma unroll
    for (int mi = 0; mi < 4; ++mi) {
        #pragma unroll
        for (int r = 0; r < 4; ++r) {
            int grow = row0 + wr * 64 + mi * 16 + quad * 4 + r;
            if (grow < M) {
                float ds = dinv[grow];
                #pragma unroll
                for (int ni = 0; ni < 4; ++ni) {
                    int gcol = col0 + wc * 64 + ni * 16 + l15;
                    C[(size_t)grow * 256 + gcol] = f2fp8(ds * acc[mi][ni][r]);
                }
            }
        }
    }
}

// ---------------- bf16 MFMA GEMM (layers 2/3); epilogue: prescale by dinv, write fp8 ----------------
__global__ __launch_bounds__(256) void k_gemm_bf16(const unsigned short* __restrict__ A,
                                                   const unsigned short* __restrict__ Bt,
                                                   const float* __restrict__ dinv,
                                                   unsigned char* __restrict__ C, int M, int K) {
    __shared__ unsigned short As[128 * 32];
    __shared__ unsigned short Bs[128 * 32];
    const int tid  = threadIdx.x;
    const int wave = tid >> 6;
    const int lane = tid & 63;
    const int row0 = blockIdx.x * 128;
    const int col0 = blockIdx.y * 128;
    const int wr = wave & 1;
    const int wc = wave >> 1;
    const int l15 = lane & 15;
    const int quad = lane >> 4;

    const int sr = tid >> 2;
    const int sk = (tid & 3) * 8;

    int ar0 = row0 + sr;        if (ar0 >= M) ar0 = M - 1;
    int ar1 = row0 + 64 + sr;   if (ar1 >= M) ar1 = M - 1;
    const int bc0 = col0 + sr;
    const int bc1 = col0 + 64 + sr;

    f32x4 acc[4][4];
    #pragma unroll
    for (int i = 0; i < 4; ++i)
        #pragma unroll
        for (int j = 0; j < 4; ++j)
            acc[i][j] = (f32x4){0.f, 0.f, 0.f, 0.f};

    for (int kb = 0; kb < K; kb += 32) {
        const unsigned short* ga0 = A + (size_t)ar0 * K + kb + sk;
        const unsigned short* ga1 = A + (size_t)ar1 * K + kb + sk;
        const unsigned short* gb0 = Bt + (size_t)bc0 * K + kb + sk;
        const unsigned short* gb1 = Bt + (size_t)bc1 * K + kb + sk;
        __builtin_amdgcn_global_load_lds((const __attribute__((address_space(1))) void*)ga0,
            (__attribute__((address_space(3))) void*)&As[wave * 512], 16, 0, 0);
        __builtin_amdgcn_global_load_lds((const __attribute__((address_space(1))) void*)ga1,
            (__attribute__((address_space(3))) void*)&As[2048 + wave * 512], 16, 0, 0);
        __builtin_amdgcn_global_load_lds((const __attribute__((address_space(1))) void*)gb0,
            (__attribute__((address_space(3))) void*)&Bs[wave * 512], 16, 0, 0);
        __builtin_amdgcn_global_load_lds((const __attribute__((address_space(1))) void*)gb1,
            (__attribute__((address_space(3))) void*)&Bs[2048 + wave * 512], 16, 0, 0);
        __syncthreads();

        bf16x8 af[4], bfr[4];
        #pragma unroll
        for (int mi = 0; mi < 4; ++mi)
            af[mi] = *(const bf16x8*)&As[(wr * 64 + mi * 16 + l15) * 32 + quad * 8];
        #pragma unroll
        for (int ni = 0; ni < 4; ++ni)
            bfr[ni] = *(const bf16x8*)&Bs[(wc * 64 + ni * 16 + l15) * 32 + quad * 8];
        #pragma unroll
        for (int mi = 0; mi < 4; ++mi)
            #pragma unroll
            for (int ni = 0; ni < 4; ++ni)
                acc[mi][ni] = __builtin_amdgcn_mfma_f32_16x16x32_bf16(af[mi], bfr[ni], acc[mi][ni], 0, 0, 0);
        __syncthreads();
    }

    #pragma unroll
    for (int mi = 0; mi < 4; ++mi) {
        #pragma unroll
        for (int r = 0; r < 4; ++r) {
            int grow = row0 + wr * 64 + mi * 16 + quad * 4 + r;
            if (grow < M) {
                float ds = dinv[grow];
                #pragma unroll
                for (int ni = 0; ni < 4; ++ni) {
                    int gcol = col0 + wc * 64 + ni * 16 + l15;
                    C[(size_t)grow * 256 + gcol] = f2fp8(ds * acc[mi][ni][r]);
                }
            }
        }
    }
}

// ---------------- aggregation over fp8 rows ----------------
__global__ __launch_bounds__(256) void k_agg(const unsigned int* __restrict__ m,   // [NN][64] dwords
                                             const float* __restrict__ bias,
                                             const float* __restrict__ dinv, const int* __restrict__ cnt,
                                             const unsigned short* __restrict__ bucket,
                                             unsigned short* __restrict__ outb,    // [NN][256] bf16
                                             int do_relu) {
    int lane = threadIdx.x & 63;
    int node = blockIdx.x * 4 + (threadIdx.x >> 6);
    if (node >= NN) return;
    const unsigned int* mrow = m + lane;
    unsigned int v = mrow[(size_t)node * 64];
    f32x2 lo = __builtin_amdgcn_cvt_pk_f32_fp8(v, false);
    f32x2 hi = __builtin_amdgcn_cvt_pk_f32_fp8(v, true);
    float4 acc = make_float4(lo.x, lo.y, hi.x, hi.y);
    int n = cnt[node]; if (n > BK) n = BK;
    const unsigned short* cs = bucket + (size_t)node * BK;
    int p = 0;
    for (; p + 8 <= n; p += 8) {
        int s0 = cs[p], s1 = cs[p + 1], s2 = cs[p + 2], s3 = cs[p + 3];
        int s4 = cs[p + 4], s5 = cs[p + 5], s6 = cs[p + 6], s7 = cs[p + 7];
        unsigned int u0 = mrow[(size_t)s0 * 64];
        unsigned int u1 = mrow[(size_t)s1 * 64];
        unsigned int u2 = mrow[(size_t)s2 * 64];
        unsigned int u3 = mrow[(size_t)s3 * 64];
        unsigned int u4 = mrow[(size_t)s4 * 64];
        unsigned int u5 = mrow[(size_t)s5 * 64];
        unsigned int u6 = mrow[(size_t)s6 * 64];
        unsigned int u7 = mrow[(size_t)s7 * 64];
        f32x2 a0 = __builtin_amdgcn_cvt_pk_f32_fp8(u0, false), b0 = __builtin_amdgcn_cvt_pk_f32_fp8(u0, true);
        f32x2 a1 = __builtin_amdgcn_cvt_pk_f32_fp8(u1, false), b1 = __builtin_amdgcn_cvt_pk_f32_fp8(u1, true);
        f32x2 a2 = __builtin_amdgcn_cvt_pk_f32_fp8(u2, false), b2 = __builtin_amdgcn_cvt_pk_f32_fp8(u2, true);
        f32x2 a3 = __builtin_amdgcn_cvt_pk_f32_fp8(u3, false), b3 = __builtin_amdgcn_cvt_pk_f32_fp8(u3, true);
        f32x2 a4 = __builtin_amdgcn_cvt_pk_f32_fp8(u4, false), b4 = __builtin_amdgcn_cvt_pk_f32_fp8(u4, true);
        f32x2 a5 = __builtin_amdgcn_cvt_pk_f32_fp8(u5, false), b5 = __builtin_amdgcn_cvt_pk_f32_fp8(u5, true);
        f32x2 a6 = __builtin_amdgcn_cvt_pk_f32_fp8(u6, false), b6 = __builtin_amdgcn_cvt_pk_f32_fp8(u6, true);
        f32x2 a7 = __builtin_amdgcn_cvt_pk_f32_fp8(u7, false), b7 = __builtin_amdgcn_cvt_pk_f32_fp8(u7, true);
        acc.x += ((a0.x + a1.x) + (a2.x + a3.x)) + ((a4.x + a5.x) + (a6.x + a7.x));
        acc.y += ((a0.y + a1.y) + (a2.y + a3.y)) + ((a4.y + a5.y) + (a6.y + a7.y));
        acc.z += ((b0.x + b1.x) + (b2.x + b3.x)) + ((b4.x + b5.x) + (b6.x + b7.x));
        acc.w += ((b0.y + b1.y) + (b2.y + b3.y)) + ((b4.y + b5.y) + (b6.y + b7.y));
    }
    for (; p < n; ++p) {
        int s = cs[p];
        unsigned int u = mrow[(size_t)s * 64];
        f32x2 a = __builtin_amdgcn_cvt_pk_f32_fp8(u, false);
        f32x2 b = __builtin_amdgcn_cvt_pk_f32_fp8(u, true);
        acc.x += a.x; acc.y += a.y; acc.z += b.x; acc.w += b.y;
    }
    float di = dinv[node];
    const float4 bb = *(const float4*)(bias + lane * 4);
    acc.x = acc.x * di + bb.x; acc.y = acc.y * di + bb.y;
    acc.z = acc.z * di + bb.z; acc.w = acc.w * di + bb.w;
    if (do_relu) {
        acc.x = fmaxf(acc.x, 0.f); acc.y = fmaxf(acc.y, 0.f);
        acc.z = fmaxf(acc.z, 0.f); acc.w = fmaxf(acc.w, 0.f);
    }
    ushort4 o;
    o.x = f2b(acc.x); o.y = f2b(acc.y); o.z = f2b(acc.z); o.w = f2b(acc.w);
    *(ushort4*)(outb + (size_t)node * 256 + lane * 4) = o;
}

// ---------------- pooling (mean over graphs), bf16 input ----------------
__global__ __launch_bounds__(256) void k_pool(const unsigned short* __restrict__ h,
                                              const int* __restrict__ batch,
                                              float* __restrict__ pooled, float* __restrict__ cnts) {
    __shared__ float pl[GG * 256];
    __shared__ float cl[GG];
    int t = threadIdx.x;
    for (int i = t; i < GG * 256; i += 256) pl[i] = 0.f;
    if (t < GG) cl[t] = 0.f;
    __syncthreads();
    int chunk = (NN + gridDim.x - 1) / gridDim.x;
    int i0 = blockIdx.x * chunk;
    int i1 = i0 + chunk; if (i1 > NN) i1 = NN;
    for (int i = i0; i < i1; ++i) {
        int g = batch[i];
        pl[g * 256 + t] += b2f(h[(size_t)i * 256 + t]);
        if (t == 0) cl[g] += 1.f;
    }
    __syncthreads();
    for (int i = t; i < GG * 256; i += 256)
        if (pl[i] != 0.f) atomicAdd(&pooled[i], pl[i]);
    if (t < GG && cl[t] != 0.f) atomicAdd(&cnts[t], cl[t]);
}

// ---------------- head ----------------
__global__ __launch_bounds__(1024) void k_head(const float* __restrict__ pooled, const float* __restrict__ cnts,
                                               const float* __restrict__ Wf, const float* __restrict__ bf,
                                               const float* __restrict__ Wp, const float* __restrict__ bp,
                                               float* __restrict__ out) {
    __shared__ float z[GG][64];
    int t = threadIdx.x;
    int g = t >> 6, j = t & 63;
    float inv = 1.f / fmaxf(cnts[g], 1.f);
    float acc = 0.f;
    for (int k = 0; k < 256; ++k) acc += pooled[g * 256 + k] * Wf[k * 64 + j];
    z[g][j] = acc * inv + bf[j];
    __syncthreads();
    if (t < GG) {
        float o = 0.f;
        for (int j2 = 0; j2 < 64; ++j2) o += z[t][j2] * Wp[j2];
        o += bp[0];
        out[t] = 1.f / (1.f + expf(-o));
    }
}

extern "C" void kernel_launch(void* const* d_in, const int* in_sizes, int n_in,
                              void* d_out, int out_size, void* d_ws, size_t ws_size,
                              hipStream_t stream) {
    const float* x   = (const float*)d_in[0];
    const int*   ei  = (const int*)d_in[1];
    const int*   bat = (const int*)d_in[2];
    const float* W1  = (const float*)d_in[3];
    const float* b1  = (const float*)d_in[4];
    const float* W2  = (const float*)d_in[5];
    const float* b2  = (const float*)d_in[6];
    const float* W3  = (const float*)d_in[7];
    const float* b3  = (const float*)d_in[8];
    const float* Wf  = (const float*)d_in[9];
    const float* bf  = (const float*)d_in[10];
    const float* Wp  = (const float*)d_in[11];
    const float* bp  = (const float*)d_in[12];
    float* out = (float*)d_out;

    char* w = (char*)d_ws;
    unsigned short* xb  = (unsigned short*)w;  w += (size_t)NN * DD * 2;   // bf16 x
    unsigned char*  mb  = (unsigned char*)w;   w += (size_t)NN * HH;       // fp8 prescaled gemm out
    unsigned short* hb  = (unsigned short*)w;  w += (size_t)NN * HH * 2;   // bf16 h (aliased: histg before agg1)
    unsigned short* hb2 = (unsigned short*)w;  w += (size_t)NN * HH * 2;   // bf16 h (aliased: offg before agg2)
    unsigned short* W1t = (unsigned short*)w;  w += (size_t)DD * HH * 2;
    unsigned short* W2t = (unsigned short*)w;  w += (size_t)HH * HH * 2;
    unsigned short* W3t = (unsigned short*)w;  w += (size_t)HH * HH * 2;
    float* dinv   = (float*)w;                 w += (size_t)NN * 4;
    int*   cnt    = (int*)w;                   w += (size_t)NN * 4;
    unsigned short* bucket = (unsigned short*)w; w += (size_t)NN * BK * 2; // 9.6 MB
    float* pooled = (float*)w;                 w += (size_t)GG * HH * 4;
    float* cnts   = (float*)w;                 w += (size_t)GG * 4;

    unsigned int* histg = (unsigned int*)hb;   // 256*25000 dwords = 25.6 MB (== hb size)
    unsigned int* offg  = (unsigned int*)hb2;  // 25.6 MB (== hb2 size)

    hipMemsetAsync(pooled, 0, (size_t)(GG * HH + GG) * 4, stream);

    // atomic-free CSR build + prep
    k_hist<<<512, 256, 0, stream>>>(ei, histg);
    k_off_cvt<<<7372, 256, 0, stream>>>(histg, offg, cnt, dinv, x, xb, W1, W2, W3, W1t, W2t, W3t);
    k_place_gemm1<<<2830, 256, 0, stream>>>(ei, offg, bucket, xb, W1t, dinv, mb);

    dim3 gg((NN + 127) / 128, 2);
    // layer 1 aggregation
    k_agg<<<(NN + 3) / 4, 256, 0, stream>>>((const unsigned int*)mb, b1, dinv, cnt, bucket, hb, 1);
    // layer 2
    k_gemm_bf16<<<gg, 256, 0, stream>>>(hb, W2t, dinv, mb, NN, HH);
    k_agg<<<(NN + 3) / 4, 256, 0, stream>>>((const unsigned int*)mb, b2, dinv, cnt, bucket, hb2, 1);
    // layer 3
    k_gemm_bf16<<<gg, 256, 0, stream>>>(hb2, W3t, dinv, mb, NN, HH);
    k_agg<<<(NN + 3) / 4, 256, 0, stream>>>((const unsigned int*)mb, b3, dinv, cnt, bucket, hb, 0);

    k_pool<<<256, 256, 0, stream>>>(hb, bat, pooled, cnts);
    k_head<<<1, 1024, 0, stream>>>(pooled, cnts, Wf, bf, Wp, bp, out);
}

// Round 11
// 560.186 us; speedup vs baseline: 1.1111x; 1.1111x over previous
//
#include <hip/hip_runtime.h>
#include <hip/hip_bf16.h>

#define NN 50000
#define EE 1600000
#define DD 512
#define HH 256
#define GG 16
#define BK 96     // bucket capacity (deg ~ Poisson(32), P(>=96) ~ 1e-18)
#define NCH 256   // edge chunks
#define CHSZ 6250 // EE / NCH

typedef __attribute__((ext_vector_type(8))) short bf16x8;
typedef __attribute__((ext_vector_type(4))) float f32x4;
typedef __attribute__((ext_vector_type(2))) float f32x2;

__device__ __forceinline__ unsigned short f2b(float f) {
    union { float f; unsigned int u; } v; v.f = f;
    unsigned int r = v.u + 0x7fffu + ((v.u >> 16) & 1u);
    return (unsigned short)(r >> 16);
}
__device__ __forceinline__ float b2f(unsigned short s) {
    union { unsigned int i; float f; } v; v.i = ((unsigned int)s) << 16; return v.f;
}
__device__ __forceinline__ unsigned char f2fp8(float f) {
    return (unsigned char)(__builtin_amdgcn_cvt_pk_fp8_f32(f, f, 0, false) & 0xff);
}

// ---------------- pass 1: per-chunk dst histograms (LDS atomics only) ----------------
__global__ __launch_bounds__(256) void k_hist(const int* __restrict__ ei, unsigned int* __restrict__ histg) {
    __shared__ unsigned int hp[12500];
    int b = blockIdx.x, t = threadIdx.x;
    int j = b >> 1, half = b & 1;
    int dlo = half * 25000;
    for (int i = t; i < 12500; i += 256) hp[i] = 0;
    __syncthreads();
    int base = j * CHSZ;
    for (int k = 0; k < 25; ++k) {
        int o = k * 256 + t;
        if (o < CHSZ) {
            int d = ei[EE + base + o];
            unsigned int ld = (unsigned)(d - dlo);
            if (ld < 25000u) atomicAdd(&hp[ld >> 1], (ld & 1) ? 65536u : 1u);
        }
    }
    __syncthreads();
    unsigned int* dst = histg + j * 25000 + half * 12500;
    for (int i = t; i < 12500; i += 256) dst[i] = hp[i];
}

// ---------------- pass 2: per-chunk exclusive offsets + cnt/dinv | x->bf16 | W->bf16^T ----------------
__global__ __launch_bounds__(256) void k_off_cvt(const unsigned int* __restrict__ histg,
                                                 unsigned int* __restrict__ offg,
                                                 int* __restrict__ cnt, float* __restrict__ dinv,
                                                 const float* __restrict__ x, unsigned short* __restrict__ xb,
                                                 const float* __restrict__ W1, const float* __restrict__ W2,
                                                 const float* __restrict__ W3, unsigned short* __restrict__ W1t,
                                                 unsigned short* __restrict__ W2t, unsigned short* __restrict__ W3t) {
    int b = blockIdx.x, t = threadIdx.x;
    if (b < 98) {
        int i = b * 256 + t;
        if (i < 25000) {
            unsigned run0 = 0, run1 = 0;
            #pragma unroll 8
            for (int j = 0; j < NCH; ++j) {
                unsigned h = histg[j * 25000 + i];
                offg[j * 25000 + i] = run0 | (run1 << 16);
                run0 += h & 0xffffu; run1 += h >> 16;
            }
            int d0 = 2 * i, d1 = 2 * i + 1;
            cnt[d0] = (int)run0; cnt[d1] = (int)run1;
            dinv[d0] = rsqrtf((float)run0 + 1.0f);
            dinv[d1] = rsqrtf((float)run1 + 1.0f);
        }
    } else if (b < 6348) {
        size_t i0 = (size_t)(b - 98) * 1024 + t;
        #pragma unroll
        for (int k = 0; k < 4; ++k) {
            size_t i = i0 + (size_t)k * 256;
            float4 v = *(const float4*)(x + i * 4);
            ushort4 o;
            o.x = f2b(v.x); o.y = f2b(v.y); o.z = f2b(v.z); o.w = f2b(v.w);
            *(ushort4*)(xb + i * 4) = o;
        }
    } else {
        int u = (b - 6348) * 256 + t;
        if (u < 131072) {
            int k = u >> 8, n = u & 255;
            W1t[(size_t)n * 512 + k] = f2b(W1[u]);
        } else if (u < 196608) {
            int q = u - 131072; int k = q >> 8, n = q & 255;
            W2t[(size_t)n * 256 + k] = f2b(W2[q]);
        } else {
            int q = u - 196608; int k = q >> 8, n = q & 255;
            W3t[(size_t)n * 256 + k] = f2b(W3[q]);
        }
    }
}

// ---------------- pass 3: atomic-free placement, unfused, XCD-partitioned ----------------
// block b: chunk j=b>>3, dst-range x8=b&7. 12.5 KB LDS -> high occupancy for latency hiding.
__global__ __launch_bounds__(256) void k_place(const int* __restrict__ ei,
                                               const unsigned int* __restrict__ offg,
                                               unsigned short* __restrict__ bucket) {
    __shared__ unsigned int cur[3125];
    int b = blockIdx.x, t = threadIdx.x;
    int x8 = b & 7, j = b >> 3;
    int lo = x8 * CHSZ;                 // lo even -> parity(ld)==parity(d)
    for (int i = t; i < 3125; i += 256) cur[i] = 0;
    __syncthreads();
    int base = j * CHSZ;
    for (int k = 0; k < 25; ++k) {
        int o = k * 256 + t;
        if (o < CHSZ) {
            int d = ei[EE + base + o];
            unsigned ld = (unsigned)(d - lo);
            if (ld < 6250u) {
                int s = ei[base + o];
                unsigned old = atomicAdd(&cur[ld >> 1], (ld & 1) ? 65536u : 1u);
                unsigned rank = (ld & 1) ? (old >> 16) : (old & 0xffffu);
                unsigned ov = offg[j * 25000 + (d >> 1)];
                unsigned pos = ((d & 1) ? (ov >> 16) : (ov & 0xffffu)) + rank;
                if (pos < BK) bucket[(size_t)d * BK + pos] = (unsigned short)s;
            }
        }
    }
}

// ---------------- bf16 MFMA GEMM; epilogue: prescale by dinv, write fp8 ----------------
__global__ __launch_bounds__(256) void k_gemm_bf16(const unsigned short* __restrict__ A,
                                                   const unsigned short* __restrict__ Bt,
                                                   const float* __restrict__ dinv,
                                                   unsigned char* __restrict__ C, int M, int K) {
    __shared__ unsigned short As[128 * 32];
    __shared__ unsigned short Bs[128 * 32];
    const int tid  = threadIdx.x;
    const int wave = tid >> 6;
    const int lane = tid & 63;
    const int row0 = blockIdx.x * 128;
    const int col0 = blockIdx.y * 128;
    const int wr = wave & 1;
    const int wc = wave >> 1;
    const int l15 = lane & 15;
    const int quad = lane >> 4;

    const int sr = tid >> 2;
    const int sk = (tid & 3) * 8;

    int ar0 = row0 + sr;        if (ar0 >= M) ar0 = M - 1;
    int ar1 = row0 + 64 + sr;   if (ar1 >= M) ar1 = M - 1;
    const int bc0 = col0 + sr;
    const int bc1 = col0 + 64 + sr;

    f32x4 acc[4][4];
    #pragma unroll
    for (int i = 0; i < 4; ++i)
        #pragma unroll
        for (int j = 0; j < 4; ++j)
            acc[i][j] = (f32x4){0.f, 0.f, 0.f, 0.f};

    for (int kb = 0; kb < K; kb += 32) {
        const unsigned short* ga0 = A + (size_t)ar0 * K + kb + sk;
        const unsigned short* ga1 = A + (size_t)ar1 * K + kb + sk;
        const unsigned short* gb0 = Bt + (size_t)bc0 * K + kb + sk;
        const unsigned short* gb1 = Bt + (size_t)bc1 * K + kb + sk;
        __builtin_amdgcn_global_load_lds((const __attribute__((address_space(1))) void*)ga0,
            (__attribute__((address_space(3))) void*)&As[wave * 512], 16, 0, 0);
        __builtin_amdgcn_global_load_lds((const __attribute__((address_space(1))) void*)ga1,
            (__attribute__((address_space(3))) void*)&As[2048 + wave * 512], 16, 0, 0);
        __builtin_amdgcn_global_load_lds((const __attribute__((address_space(1))) void*)gb0,
            (__attribute__((address_space(3))) void*)&Bs[wave * 512], 16, 0, 0);
        __builtin_amdgcn_global_load_lds((const __attribute__((address_space(1))) void*)gb1,
            (__attribute__((address_space(3))) void*)&Bs[2048 + wave * 512], 16, 0, 0);
        __syncthreads();

        bf16x8 af[4], bfr[4];
        #pragma unroll
        for (int mi = 0; mi < 4; ++mi)
            af[mi] = *(const bf16x8*)&As[(wr * 64 + mi * 16 + l15) * 32 + quad * 8];
        #pragma unroll
        for (int ni = 0; ni < 4; ++ni)
            bfr[ni] = *(const bf16x8*)&Bs[(wc * 64 + ni * 16 + l15) * 32 + quad * 8];
        #pragma unroll
        for (int mi = 0; mi < 4; ++mi)
            #pragma unroll
            for (int ni = 0; ni < 4; ++ni)
                acc[mi][ni] = __builtin_amdgcn_mfma_f32_16x16x32_bf16(af[mi], bfr[ni], acc[mi][ni], 0, 0, 0);
        __syncthreads();
    }

    #pragma unroll
    for (int mi = 0; mi < 4; ++mi) {
        #pragma unroll
        for (int r = 0; r < 4; ++r) {
            int grow = row0 + wr * 64 + mi * 16 + quad * 4 + r;
            if (grow < M) {
                float ds = dinv[grow];
                #pragma unroll
                for (int ni = 0; ni < 4; ++ni) {
                    int gcol = col0 + wc * 64 + ni * 16 + l15;
                    C[(size_t)grow * 256 + gcol] = f2fp8(ds * acc[mi][ni][r]);
                }
            }
        }
    }
}

// ---------------- aggregation over fp8 rows ----------------
__global__ __launch_bounds__(256) void k_agg(const unsigned int* __restrict__ m,   // [NN][64] dwords
                                             const float* __restrict__ bias,
                                             const float* __restrict__ dinv, const int* __restrict__ cnt,
                                             const unsigned short* __restrict__ bucket,
                                             unsigned short* __restrict__ outb,    // [NN][256] bf16
                                             int do_relu) {
    int lane = threadIdx.x & 63;
    int node = blockIdx.x * 4 + (threadIdx.x >> 6);
    if (node >= NN) return;
    const unsigned int* mrow = m + lane;
    unsigned int v = mrow[(size_t)node * 64];
    f32x2 lo = __builtin_amdgcn_cvt_pk_f32_fp8(v, false);
    f32x2 hi = __builtin_amdgcn_cvt_pk_f32_fp8(v, true);
    float4 acc = make_float4(lo.x, lo.y, hi.x, hi.y);
    int n = cnt[node]; if (n > BK) n = BK;
    const unsigned short* cs = bucket + (size_t)node * BK;
    int p = 0;
    for (; p + 8 <= n; p += 8) {
        int s0 = cs[p], s1 = cs[p + 1], s2 = cs[p + 2], s3 = cs[p + 3];
        int s4 = cs[p + 4], s5 = cs[p + 5], s6 = cs[p + 6], s7 = cs[p + 7];
        unsigned int u0 = mrow[(size_t)s0 * 64];
        unsigned int u1 = mrow[(size_t)s1 * 64];
        unsigned int u2 = mrow[(size_t)s2 * 64];
        unsigned int u3 = mrow[(size_t)s3 * 64];
        unsigned int u4 = mrow[(size_t)s4 * 64];
        unsigned int u5 = mrow[(size_t)s5 * 64];
        unsigned int u6 = mrow[(size_t)s6 * 64];
        unsigned int u7 = mrow[(size_t)s7 * 64];
        f32x2 a0 = __builtin_amdgcn_cvt_pk_f32_fp8(u0, false), b0 = __builtin_amdgcn_cvt_pk_f32_fp8(u0, true);
        f32x2 a1 = __builtin_amdgcn_cvt_pk_f32_fp8(u1, false), b1 = __builtin_amdgcn_cvt_pk_f32_fp8(u1, true);
        f32x2 a2 = __builtin_amdgcn_cvt_pk_f32_fp8(u2, false), b2 = __builtin_amdgcn_cvt_pk_f32_fp8(u2, true);
        f32x2 a3 = __builtin_amdgcn_cvt_pk_f32_fp8(u3, false), b3 = __builtin_amdgcn_cvt_pk_f32_fp8(u3, true);
        f32x2 a4 = __builtin_amdgcn_cvt_pk_f32_fp8(u4, false), b4 = __builtin_amdgcn_cvt_pk_f32_fp8(u4, true);
        f32x2 a5 = __builtin_amdgcn_cvt_pk_f32_fp8(u5, false), b5 = __builtin_amdgcn_cvt_pk_f32_fp8(u5, true);
        f32x2 a6 = __builtin_amdgcn_cvt_pk_f32_fp8(u6, false), b6 = __builtin_amdgcn_cvt_pk_f32_fp8(u6, true);
        f32x2 a7 = __builtin_amdgcn_cvt_pk_f32_fp8(u7, false), b7 = __builtin_amdgcn_cvt_pk_f32_fp8(u7, true);
        acc.x += ((a0.x + a1.x) + (a2.x + a3.x)) + ((a4.x + a5.x) + (a6.x + a7.x));
        acc.y += ((a0.y + a1.y) + (a2.y + a3.y)) + ((a4.y + a5.y) + (a6.y + a7.y));
        acc.z += ((b0.x + b1.x) + (b2.x + b3.x)) + ((b4.x + b5.x) + (b6.x + b7.x));
        acc.w += ((b0.y + b1.y) + (b2.y + b3.y)) + ((b4.y + b5.y) + (b6.y + b7.y));
    }
    for (; p < n; ++p) {
        int s = cs[p];
        unsigned int u = mrow[(size_t)s * 64];
        f32x2 a = __builtin_amdgcn_cvt_pk_f32_fp8(u, false);
        f32x2 b = __builtin_amdgcn_cvt_pk_f32_fp8(u, true);
        acc.x += a.x; acc.y += a.y; acc.z += b.x; acc.w += b.y;
    }
    float di = dinv[node];
    const float4 bb = *(const float4*)(bias + lane * 4);
    acc.x = acc.x * di + bb.x; acc.y = acc.y * di + bb.y;
    acc.z = acc.z * di + bb.z; acc.w = acc.w * di + bb.w;
    if (do_relu) {
        acc.x = fmaxf(acc.x, 0.f); acc.y = fmaxf(acc.y, 0.f);
        acc.z = fmaxf(acc.z, 0.f); acc.w = fmaxf(acc.w, 0.f);
    }
    ushort4 o;
    o.x = f2b(acc.x); o.y = f2b(acc.y); o.z = f2b(acc.z); o.w = f2b(acc.w);
    *(ushort4*)(outb + (size_t)node * 256 + lane * 4) = o;
}

// ---------------- pooling: register-accumulated ushort4, batch sorted so flushes rare ----------------
__global__ __launch_bounds__(256) void k_pool(const unsigned short* __restrict__ h,
                                              const int* __restrict__ batch,
                                              float* __restrict__ pooled, float* __restrict__ cnts) {
    __shared__ float pl[GG * 256];
    __shared__ float cl[GG];
    int t = threadIdx.x;
    for (int i = t; i < GG * 256; i += 256) pl[i] = 0.f;
    if (t < GG) cl[t] = 0.f;
    __syncthreads();
    int sub = t >> 6;             // 4 node-subgroups
    int f4 = (t & 63) * 4;        // feature base
    int chunk = (NN + gridDim.x - 1) / gridDim.x;
    int i0 = blockIdx.x * chunk;
    int i1 = i0 + chunk; if (i1 > NN) i1 = NN;
    int gcur = -1;
    float a0 = 0.f, a1 = 0.f, a2 = 0.f, a3 = 0.f, cr = 0.f;
    for (int i = i0 + sub; i < i1; i += 4) {
        int g = batch[i];
        if (g != gcur) {
            if (gcur >= 0) {
                atomicAdd(&pl[gcur * 256 + f4 + 0], a0);
                atomicAdd(&pl[gcur * 256 + f4 + 1], a1);
                atomicAdd(&pl[gcur * 256 + f4 + 2], a2);
                atomicAdd(&pl[gcur * 256 + f4 + 3], a3);
                if ((t & 63) == 0) atomicAdd(&cl[gcur], cr);
            }
            gcur = g; a0 = a1 = a2 = a3 = 0.f; cr = 0.f;
        }
        ushort4 u = *(const ushort4*)(h + (size_t)i * 256 + f4);
        a0 += b2f(u.x); a1 += b2f(u.y); a2 += b2f(u.z); a3 += b2f(u.w);
        cr += 1.f;
    }
    if (gcur >= 0) {
        atomicAdd(&pl[gcur * 256 + f4 + 0], a0);
        atomicAdd(&pl[gcur * 256 + f4 + 1], a1);
        atomicAdd(&pl[gcur * 256 + f4 + 2], a2);
        atomicAdd(&pl[gcur * 256 + f4 + 3], a3);
        if ((t & 63) == 0) atomicAdd(&cl[gcur], cr);
    }
    __syncthreads();
    for (int i = t; i < GG * 256; i += 256)
        if (pl[i] != 0.f) atomicAdd(&pooled[i], pl[i]);
    if (t < GG && cl[t] != 0.f) atomicAdd(&cnts[t], cl[t]);
}

// ---------------- head ----------------
__global__ __launch_bounds__(1024) void k_head(const float* __restrict__ pooled, const float* __restrict__ cnts,
                                               const float* __restrict__ Wf, const float* __restrict__ bf,
                                               const float* __restrict__ Wp, const float* __restrict__ bp,
                                               float* __restrict__ out) {
    __shared__ float z[GG][64];
    int t = threadIdx.x;
    int g = t >> 6, j = t & 63;
    float inv = 1.f / fmaxf(cnts[g], 1.f);
    float acc = 0.f;
    for (int k = 0; k < 256; ++k) acc += pooled[g * 256 + k] * Wf[k * 64 + j];
    z[g][j] = acc * inv + bf[j];
    __syncthreads();
    if (t < GG) {
        float o = 0.f;
        for (int j2 = 0; j2 < 64; ++j2) o += z[t][j2] * Wp[j2];
        o += bp[0];
        out[t] = 1.f / (1.f + expf(-o));
    }
}

extern "C" void kernel_launch(void* const* d_in, const int* in_sizes, int n_in,
                              void* d_out, int out_size, void* d_ws, size_t ws_size,
                              hipStream_t stream) {
    const float* x   = (const float*)d_in[0];
    const int*   ei  = (const int*)d_in[1];
    const int*   bat = (const int*)d_in[2];
    const float* W1  = (const float*)d_in[3];
    const float* b1  = (const float*)d_in[4];
    const float* W2  = (const float*)d_in[5];
    const float* b2  = (const float*)d_in[6];
    const float* W3  = (const float*)d_in[7];
    const float* b3  = (const float*)d_in[8];
    const float* Wf  = (const float*)d_in[9];
    const float* bf  = (const float*)d_in[10];
    const float* Wp  = (const float*)d_in[11];
    const float* bp  = (const float*)d_in[12];
    float* out = (float*)d_out;

    char* w = (char*)d_ws;
    unsigned short* xb  = (unsigned short*)w;  w += (size_t)NN * DD * 2;   // bf16 x
    unsigned char*  mb  = (unsigned char*)w;   w += (size_t)NN * HH;       // fp8 prescaled gemm out
    unsigned short* hb  = (unsigned short*)w;  w += (size_t)NN * HH * 2;   // bf16 h (aliased: histg before agg1)
    unsigned short* hb2 = (unsigned short*)w;  w += (size_t)NN * HH * 2;   // bf16 h (aliased: offg before agg2)
    unsigned short* W1t = (unsigned short*)w;  w += (size_t)DD * HH * 2;
    unsigned short* W2t = (unsigned short*)w;  w += (size_t)HH * HH * 2;
    unsigned short* W3t = (unsigned short*)w;  w += (size_t)HH * HH * 2;
    float* dinv   = (float*)w;                 w += (size_t)NN * 4;
    int*   cnt    = (int*)w;                   w += (size_t)NN * 4;
    unsigned short* bucket = (unsigned short*)w; w += (size_t)NN * BK * 2; // 9.6 MB
    float* pooled = (float*)w;                 w += (size_t)GG * HH * 4;
    float* cnts   = (float*)w;                 w += (size_t)GG * 4;

    unsigned int* histg = (unsigned int*)hb;   // 256*25000 dwords = 25.6 MB
    unsigned int* offg  = (unsigned int*)hb2;  // 25.6 MB

    hipMemsetAsync(pooled, 0, (size_t)(GG * HH + GG) * 4, stream);

    // atomic-free CSR build + prep
    k_hist<<<512, 256, 0, stream>>>(ei, histg);
    k_off_cvt<<<7372, 256, 0, stream>>>(histg, offg, cnt, dinv, x, xb, W1, W2, W3, W1t, W2t, W3t);
    k_place<<<2048, 256, 0, stream>>>(ei, offg, bucket);

    dim3 gg((NN + 127) / 128, 2);
    // layer 1
    k_gemm_bf16<<<gg, 256, 0, stream>>>(xb, W1t, dinv, mb, NN, DD);
    k_agg<<<(NN + 3) / 4, 256, 0, stream>>>((const unsigned int*)mb, b1, dinv, cnt, bucket, hb, 1);
    // layer 2
    k_gemm_bf16<<<gg, 256, 0, stream>>>(hb, W2t, dinv, mb, NN, HH);
    k_agg<<<(NN + 3) / 4, 256, 0, stream>>>((const unsigned int*)mb, b2, dinv, cnt, bucket, hb2, 1);
    // layer 3
    k_gemm_bf16<<<gg, 256, 0, stream>>>(hb2, W3t, dinv, mb, NN, HH);
    k_agg<<<(NN + 3) / 4, 256, 0, stream>>>((const unsigned int*)mb, b3, dinv, cnt, bucket, hb, 0);

    k_pool<<<256, 256, 0, stream>>>(hb, bat, pooled, cnts);
    k_head<<<1, 1024, 0, stream>>>(pooled, cnts, Wf, bf, Wp, bp, out);
}

// Round 12
// 555.169 us; speedup vs baseline: 1.1211x; 1.0090x over previous
//
#include <hip/hip_runtime.h>
#include <hip/hip_bf16.h>

#define NN 50000
#define EE 1600000
#define DD 512
#define HH 256
#define GG 16
#define BK 96     // bucket capacity (deg ~ Poisson(32), P(>=96) ~ 1e-18)
#define NCH 256   // edge chunks
#define CHSZ 6250 // EE / NCH

typedef long fp8x8;                                         // 8 fp8 bytes = 2 VGPRs
typedef __attribute__((ext_vector_type(4))) float f32x4;
typedef __attribute__((ext_vector_type(2))) float f32x2;

__device__ __forceinline__ float b2f(unsigned short s) {
    union { unsigned int i; float f; } v; v.i = ((unsigned int)s) << 16; return v.f;
}
__device__ __forceinline__ unsigned char f2fp8(float f) {
    return (unsigned char)(__builtin_amdgcn_cvt_pk_fp8_f32(f, f, 0, false) & 0xff);
}
__device__ __forceinline__ unsigned int pk4fp8(float a, float b, float c, float d) {
    unsigned int r = __builtin_amdgcn_cvt_pk_fp8_f32(a, b, 0, false);
    return __builtin_amdgcn_cvt_pk_fp8_f32(c, d, r, true);
}

// ---------------- pass 1: per-chunk dst histograms (LDS atomics only) ----------------
__global__ __launch_bounds__(256) void k_hist(const int* __restrict__ ei, unsigned int* __restrict__ histg) {
    __shared__ unsigned int hp[12500];
    int b = blockIdx.x, t = threadIdx.x;
    int j = b >> 1, half = b & 1;
    int dlo = half * 25000;
    for (int i = t; i < 12500; i += 256) hp[i] = 0;
    __syncthreads();
    int base = j * CHSZ;
    for (int k = 0; k < 25; ++k) {
        int o = k * 256 + t;
        if (o < CHSZ) {
            int d = ei[EE + base + o];
            unsigned int ld = (unsigned)(d - dlo);
            if (ld < 25000u) atomicAdd(&hp[ld >> 1], (ld & 1) ? 65536u : 1u);
        }
    }
    __syncthreads();
    unsigned int* dst = histg + j * 25000 + half * 12500;
    for (int i = t; i < 12500; i += 256) dst[i] = hp[i];
}

// ---------------- pass 2: per-chunk exclusive offsets + cnt/dinv | x->fp8 | W->fp8^T ----------------
// blocks [0,98): offsets. [98,6348): x convert (16 floats/thread -> 16 fp8 bytes).
// [6348,7372): weight transpose-convert.
__global__ __launch_bounds__(256) void k_off_cvt(const unsigned int* __restrict__ histg,
                                                 unsigned int* __restrict__ offg,
                                                 int* __restrict__ cnt, float* __restrict__ dinv,
                                                 const float* __restrict__ x, unsigned char* __restrict__ xb,
                                                 const float* __restrict__ W1, const float* __restrict__ W2,
                                                 const float* __restrict__ W3, unsigned char* __restrict__ W1t,
                                                 unsigned char* __restrict__ W2t, unsigned char* __restrict__ W3t) {
    int b = blockIdx.x, t = threadIdx.x;
    if (b < 98) {
        int i = b * 256 + t;
        if (i < 25000) {
            unsigned run0 = 0, run1 = 0;
            #pragma unroll 8
            for (int j = 0; j < NCH; ++j) {
                unsigned h = histg[j * 25000 + i];
                offg[j * 25000 + i] = run0 | (run1 << 16);
                run0 += h & 0xffffu; run1 += h >> 16;
            }
            int d0 = 2 * i, d1 = 2 * i + 1;
            cnt[d0] = (int)run0; cnt[d1] = (int)run1;
            dinv[d0] = rsqrtf((float)run0 + 1.0f);
            dinv[d1] = rsqrtf((float)run1 + 1.0f);
        }
    } else if (b < 6348) {
        size_t i0 = ((size_t)(b - 98) * 256 + t) * 16;   // 16 floats per thread
        float4 v0 = *(const float4*)(x + i0);
        float4 v1 = *(const float4*)(x + i0 + 4);
        float4 v2 = *(const float4*)(x + i0 + 8);
        float4 v3 = *(const float4*)(x + i0 + 12);
        uint4 o;
        o.x = pk4fp8(v0.x, v0.y, v0.z, v0.w);
        o.y = pk4fp8(v1.x, v1.y, v1.z, v1.w);
        o.z = pk4fp8(v2.x, v2.y, v2.z, v2.w);
        o.w = pk4fp8(v3.x, v3.y, v3.z, v3.w);
        *(uint4*)(xb + i0) = o;
    } else {
        int u = (b - 6348) * 256 + t;
        if (u < 131072) {
            int k = u >> 8, n = u & 255;
            W1t[(size_t)n * 512 + k] = f2fp8(W1[u]);
        } else if (u < 196608) {
            int q = u - 131072; int k = q >> 8, n = q & 255;
            W2t[(size_t)n * 256 + k] = f2fp8(W2[q]);
        } else {
            int q = u - 196608; int k = q >> 8, n = q & 255;
            W3t[(size_t)n * 256 + k] = f2fp8(W3[q]);
        }
    }
}

// ---------------- pass 3: atomic-free placement, XCD-partitioned ----------------
__global__ __launch_bounds__(256) void k_place(const int* __restrict__ ei,
                                               const unsigned int* __restrict__ offg,
                                               unsigned short* __restrict__ bucket) {
    __shared__ unsigned int cur[3125];
    int b = blockIdx.x, t = threadIdx.x;
    int x8 = b & 7, j = b >> 3;
    int lo = x8 * CHSZ;                 // lo even -> parity(ld)==parity(d)
    for (int i = t; i < 3125; i += 256) cur[i] = 0;
    __syncthreads();
    int base = j * CHSZ;
    for (int k = 0; k < 25; ++k) {
        int o = k * 256 + t;
        if (o < CHSZ) {
            int d = ei[EE + base + o];
            unsigned ld = (unsigned)(d - lo);
            if (ld < 6250u) {
                int s = ei[base + o];
                unsigned old = atomicAdd(&cur[ld >> 1], (ld & 1) ? 65536u : 1u);
                unsigned rank = (ld & 1) ? (old >> 16) : (old & 0xffffu);
                unsigned ov = offg[j * 25000 + (d >> 1)];
                unsigned pos = ((d & 1) ? (ov >> 16) : (ov & 0xffffu)) + rank;
                if (pos < BK) bucket[(size_t)d * BK + pos] = (unsigned short)s;
            }
        }
    }
}

// ---------------- fp8 MFMA GEMM: C = fp8(dinv[row] * (A @ Bt^T)) ----------------
// A [M][K] fp8, Bt [256][K] fp8. Tile 128x128, BK=32 (32 B staging rows).
__global__ __launch_bounds__(256) void k_gemm_fp8(const unsigned char* __restrict__ A,
                                                  const unsigned char* __restrict__ Bt,
                                                  const float* __restrict__ dinv,
                                                  unsigned char* __restrict__ C, int M, int K) {
    __shared__ unsigned char As[128 * 32];
    __shared__ unsigned char Bs[128 * 32];
    const int tid  = threadIdx.x;
    const int wave = tid >> 6;
    const int lane = tid & 63;
    const int row0 = blockIdx.x * 128;
    const int col0 = blockIdx.y * 128;
    const int wr = wave & 1;
    const int wc = wave >> 1;
    const int l15 = lane & 15;
    const int quad = lane >> 4;

    const int sr = tid >> 1;          // 0..127
    const int sk = (tid & 1) * 16;    // byte offset in k

    int ar = row0 + sr; if (ar >= M) ar = M - 1;
    const int bc = col0 + sr;

    f32x4 acc[4][4];
    #pragma unroll
    for (int i = 0; i < 4; ++i)
        #pragma unroll
        for (int j = 0; j < 4; ++j)
            acc[i][j] = (f32x4){0.f, 0.f, 0.f, 0.f};

    for (int kb = 0; kb < K; kb += 32) {
        const unsigned char* ga = A + (size_t)ar * K + kb + sk;
        const unsigned char* gb = Bt + (size_t)bc * K + kb + sk;
        __builtin_amdgcn_global_load_lds((const __attribute__((address_space(1))) void*)ga,
            (__attribute__((address_space(3))) void*)&As[wave * 1024], 16, 0, 0);
        __builtin_amdgcn_global_load_lds((const __attribute__((address_space(1))) void*)gb,
            (__attribute__((address_space(3))) void*)&Bs[wave * 1024], 16, 0, 0);
        __syncthreads();

        fp8x8 af[4], bfr[4];
        #pragma unroll
        for (int mi = 0; mi < 4; ++mi)
            af[mi] = *(const fp8x8*)&As[(wr * 64 + mi * 16 + l15) * 32 + quad * 8];
        #pragma unroll
        for (int ni = 0; ni < 4; ++ni)
            bfr[ni] = *(const fp8x8*)&Bs[(wc * 64 + ni * 16 + l15) * 32 + quad * 8];
        #pragma unroll
        for (int mi = 0; mi < 4; ++mi)
            #pragma unroll
            for (int ni = 0; ni < 4; ++ni)
                acc[mi][ni] = __builtin_amdgcn_mfma_f32_16x16x32_fp8_fp8(af[mi], bfr[ni], acc[mi][ni], 0, 0, 0);
        __syncthreads();
    }

    #pragma unroll
    for (int mi = 0; mi < 4; ++mi) {
        #pragma unroll
        for (int r = 0; r < 4; ++r) {
            int grow = row0 + wr * 64 + mi * 16 + quad * 4 + r;
            if (grow < M) {
                float ds = dinv[grow];
                #pragma unroll
                for (int ni = 0; ni < 4; ++ni) {
                    int gcol = col0 + wc * 64 + ni * 16 + l15;
                    C[(size_t)grow * 256 + gcol] = f2fp8(ds * acc[mi][ni][r]);
                }
            }
        }
    }
}

// ---------------- aggregation over fp8 rows; fp8 h output ----------------
__global__ __launch_bounds__(256) void k_agg(const unsigned int* __restrict__ m,   // [NN][64] dwords
                                             const float* __restrict__ bias,
                                             const float* __restrict__ dinv, const int* __restrict__ cnt,
                                             const unsigned short* __restrict__ bucket,
                                             unsigned int* __restrict__ outb,      // [NN][64] dwords fp8
                                             int do_relu) {
    int lane = threadIdx.x & 63;
    int node = blockIdx.x * 4 + (threadIdx.x >> 6);
    if (node >= NN) return;
    const unsigned int* mrow = m + lane;
    unsigned int v = mrow[(size_t)node * 64];
    f32x2 lo = __builtin_amdgcn_cvt_pk_f32_fp8(v, false);
    f32x2 hi = __builtin_amdgcn_cvt_pk_f32_fp8(v, true);
    float4 acc = make_float4(lo.x, lo.y, hi.x, hi.y);
    int n = cnt[node]; if (n > BK) n = BK;
    const unsigned short* cs = bucket + (size_t)node * BK;
    int p = 0;
    for (; p + 8 <= n; p += 8) {
        int s0 = cs[p], s1 = cs[p + 1], s2 = cs[p + 2], s3 = cs[p + 3];
        int s4 = cs[p + 4], s5 = cs[p + 5], s6 = cs[p + 6], s7 = cs[p + 7];
        unsigned int u0 = mrow[(size_t)s0 * 64];
        unsigned int u1 = mrow[(size_t)s1 * 64];
        unsigned int u2 = mrow[(size_t)s2 * 64];
        unsigned int u3 = mrow[(size_t)s3 * 64];
        unsigned int u4 = mrow[(size_t)s4 * 64];
        unsigned int u5 = mrow[(size_t)s5 * 64];
        unsigned int u6 = mrow[(size_t)s6 * 64];
        unsigned int u7 = mrow[(size_t)s7 * 64];
        f32x2 a0 = __builtin_amdgcn_cvt_pk_f32_fp8(u0, false), b0 = __builtin_amdgcn_cvt_pk_f32_fp8(u0, true);
        f32x2 a1 = __builtin_amdgcn_cvt_pk_f32_fp8(u1, false), b1 = __builtin_amdgcn_cvt_pk_f32_fp8(u1, true);
        f32x2 a2 = __builtin_amdgcn_cvt_pk_f32_fp8(u2, false), b2 = __builtin_amdgcn_cvt_pk_f32_fp8(u2, true);
        f32x2 a3 = __builtin_amdgcn_cvt_pk_f32_fp8(u3, false), b3 = __builtin_amdgcn_cvt_pk_f32_fp8(u3, true);
        f32x2 a4 = __builtin_amdgcn_cvt_pk_f32_fp8(u4, false), b4 = __builtin_amdgcn_cvt_pk_f32_fp8(u4, true);
        f32x2 a5 = __builtin_amdgcn_cvt_pk_f32_fp8(u5, false), b5 = __builtin_amdgcn_cvt_pk_f32_fp8(u5, true);
        f32x2 a6 = __builtin_amdgcn_cvt_pk_f32_fp8(u6, false), b6 = __builtin_amdgcn_cvt_pk_f32_fp8(u6, true);
        f32x2 a7 = __builtin_amdgcn_cvt_pk_f32_fp8(u7, false), b7 = __builtin_amdgcn_cvt_pk_f32_fp8(u7, true);
        acc.x += ((a0.x + a1.x) + (a2.x + a3.x)) + ((a4.x + a5.x) + (a6.x + a7.x));
        acc.y += ((a0.y + a1.y) + (a2.y + a3.y)) + ((a4.y + a5.y) + (a6.y + a7.y));
        acc.z += ((b0.x + b1.x) + (b2.x + b3.x)) + ((b4.x + b5.x) + (b6.x + b7.x));
        acc.w += ((b0.y + b1.y) + (b2.y + b3.y)) + ((b4.y + b5.y) + (b6.y + b7.y));
    }
    for (; p < n; ++p) {
        int s = cs[p];
        unsigned int u = mrow[(size_t)s * 64];
        f32x2 a = __builtin_amdgcn_cvt_pk_f32_fp8(u, false);
        f32x2 b = __builtin_amdgcn_cvt_pk_f32_fp8(u, true);
        acc.x += a.x; acc.y += a.y; acc.z += b.x; acc.w += b.y;
    }
    float di = dinv[node];
    const float4 bb = *(const float4*)(bias + lane * 4);
    acc.x = acc.x * di + bb.x; acc.y = acc.y * di + bb.y;
    acc.z = acc.z * di + bb.z; acc.w = acc.w * di + bb.w;
    if (do_relu) {
        acc.x = fmaxf(acc.x, 0.f); acc.y = fmaxf(acc.y, 0.f);
        acc.z = fmaxf(acc.z, 0.f); acc.w = fmaxf(acc.w, 0.f);
    }
    outb[(size_t)node * 64 + lane] = pk4fp8(acc.x, acc.y, acc.z, acc.w);
}

// ---------------- pooling over fp8 h (mean over graphs) ----------------
__global__ __launch_bounds__(256) void k_pool(const unsigned int* __restrict__ h,  // [NN][64] dwords
                                              const int* __restrict__ batch,
                                              float* __restrict__ pooled, float* __restrict__ cnts) {
    __shared__ float pl[GG * 256];
    __shared__ float cl[GG];
    int t = threadIdx.x;
    for (int i = t; i < GG * 256; i += 256) pl[i] = 0.f;
    if (t < GG) cl[t] = 0.f;
    __syncthreads();
    int sub = t >> 6;
    int fd = t & 63;              // feature dword
    int chunk = (NN + gridDim.x - 1) / gridDim.x;
    int i0 = blockIdx.x * chunk;
    int i1 = i0 + chunk; if (i1 > NN) i1 = NN;
    int gcur = -1;
    float a0 = 0.f, a1 = 0.f, a2 = 0.f, a3 = 0.f, cr = 0.f;
    for (int i = i0 + sub; i < i1; i += 4) {
        int g = batch[i];
        if (g != gcur) {
            if (gcur >= 0) {
                atomicAdd(&pl[gcur * 256 + fd * 4 + 0], a0);
                atomicAdd(&pl[gcur * 256 + fd * 4 + 1], a1);
                atomicAdd(&pl[gcur * 256 + fd * 4 + 2], a2);
                atomicAdd(&pl[gcur * 256 + fd * 4 + 3], a3);
                if (fd == 0) atomicAdd(&cl[gcur], cr);
            }
            gcur = g; a0 = a1 = a2 = a3 = 0.f; cr = 0.f;
        }
        unsigned int u = h[(size_t)i * 64 + fd];
        f32x2 lo = __builtin_amdgcn_cvt_pk_f32_fp8(u, false);
        f32x2 hi = __builtin_amdgcn_cvt_pk_f32_fp8(u, true);
        a0 += lo.x; a1 += lo.y; a2 += hi.x; a3 += hi.y;
        cr += 1.f;
    }
    if (gcur >= 0) {
        atomicAdd(&pl[gcur * 256 + fd * 4 + 0], a0);
        atomicAdd(&pl[gcur * 256 + fd * 4 + 1], a1);
        atomicAdd(&pl[gcur * 256 + fd * 4 + 2], a2);
        atomicAdd(&pl[gcur * 256 + fd * 4 + 3], a3);
        if (fd == 0) atomicAdd(&cl[gcur], cr);
    }
    __syncthreads();
    for (int i = t; i < GG * 256; i += 256)
        if (pl[i] != 0.f) atomicAdd(&pooled[i], pl[i]);
    if (t < GG && cl[t] != 0.f) atomicAdd(&cnts[t], cl[t]);
}

// ---------------- head ----------------
__global__ __launch_bounds__(1024) void k_head(const float* __restrict__ pooled, const float* __restrict__ cnts,
                                               const float* __restrict__ Wf, const float* __restrict__ bf,
                                               const float* __restrict__ Wp, const float* __restrict__ bp,
                                               float* __restrict__ out) {
    __shared__ float z[GG][64];
    int t = threadIdx.x;
    int g = t >> 6, j = t & 63;
    float inv = 1.f / fmaxf(cnts[g], 1.f);
    float acc = 0.f;
    for (int k = 0; k < 256; ++k) acc += pooled[g * 256 + k] * Wf[k * 64 + j];
    z[g][j] = acc * inv + bf[j];
    __syncthreads();
    if (t < GG) {
        float o = 0.f;
        for (int j2 = 0; j2 < 64; ++j2) o += z[t][j2] * Wp[j2];
        o += bp[0];
        out[t] = 1.f / (1.f + expf(-o));
    }
}

extern "C" void kernel_launch(void* const* d_in, const int* in_sizes, int n_in,
                              void* d_out, int out_size, void* d_ws, size_t ws_size,
                              hipStream_t stream) {
    const float* x   = (const float*)d_in[0];
    const int*   ei  = (const int*)d_in[1];
    const int*   bat = (const int*)d_in[2];
    const float* W1  = (const float*)d_in[3];
    const float* b1  = (const float*)d_in[4];
    const float* W2  = (const float*)d_in[5];
    const float* b2  = (const float*)d_in[6];
    const float* W3  = (const float*)d_in[7];
    const float* b3  = (const float*)d_in[8];
    const float* Wf  = (const float*)d_in[9];
    const float* bf  = (const float*)d_in[10];
    const float* Wp  = (const float*)d_in[11];
    const float* bp  = (const float*)d_in[12];
    float* out = (float*)d_out;

    char* w = (char*)d_ws;
    unsigned char* xb  = (unsigned char*)w;  w += (size_t)NN * DD;        // fp8 x, 25.6 MB
    unsigned char* mb  = (unsigned char*)w;  w += (size_t)NN * HH;        // fp8 prescaled gemm out
    unsigned char* hb  = (unsigned char*)w;  w += (size_t)NCH * 25000 * 4; // 25.6 MB: histg, then fp8 h (12.8)
    unsigned char* hb2 = (unsigned char*)w;  w += (size_t)NCH * 25000 * 4; // 25.6 MB: offg, then fp8 h
    unsigned char* W1t = (unsigned char*)w;  w += (size_t)DD * HH;
    unsigned char* W2t = (unsigned char*)w;  w += (size_t)HH * HH;
    unsigned char* W3t = (unsigned char*)w;  w += (size_t)HH * HH;
    float* dinv   = (float*)w;               w += (size_t)NN * 4;
    int*   cnt    = (int*)w;                 w += (size_t)NN * 4;
    unsigned short* bucket = (unsigned short*)w; w += (size_t)NN * BK * 2; // 9.6 MB
    float* pooled = (float*)w;               w += (size_t)GG * HH * 4;
    float* cnts   = (float*)w;               w += (size_t)GG * 4;

    unsigned int* histg = (unsigned int*)hb;
    unsigned int* offg  = (unsigned int*)hb2;

    hipMemsetAsync(pooled, 0, (size_t)(GG * HH + GG) * 4, stream);

    // atomic-free CSR build + prep (all fp8 converts fused)
    k_hist<<<512, 256, 0, stream>>>(ei, histg);
    k_off_cvt<<<7372, 256, 0, stream>>>(histg, offg, cnt, dinv, x, xb, W1, W2, W3, W1t, W2t, W3t);
    k_place<<<2048, 256, 0, stream>>>(ei, offg, bucket);

    dim3 gg((NN + 127) / 128, 2);
    // layer 1
    k_gemm_fp8<<<gg, 256, 0, stream>>>(xb, W1t, dinv, mb, NN, DD);
    k_agg<<<(NN + 3) / 4, 256, 0, stream>>>((const unsigned int*)mb, b1, dinv, cnt, bucket,
                                            (unsigned int*)hb, 1);
    // layer 2
    k_gemm_fp8<<<gg, 256, 0, stream>>>(hb, W2t, dinv, mb, NN, HH);
    k_agg<<<(NN + 3) / 4, 256, 0, stream>>>((const unsigned int*)mb, b2, dinv, cnt, bucket,
                                            (unsigned int*)hb2, 1);
    // layer 3
    k_gemm_fp8<<<gg, 256, 0, stream>>>(hb2, W3t, dinv, mb, NN, HH);
    k_agg<<<(NN + 3) / 4, 256, 0, stream>>>((const unsigned int*)mb, b3, dinv, cnt, bucket,
                                            (unsigned int*)hb, 0);

    k_pool<<<256, 256, 0, stream>>>((const unsigned int*)hb, bat, pooled, cnts);
    k_head<<<1, 1024, 0, stream>>>(pooled, cnts, Wf, bf, Wp, bp, out);
}